// Round 16
// baseline (140.897 us; speedup 1.0000x reference)
//
#include <hip/hip_runtime.h>

#define Bb 64
#define Ss 1000
#define Kk 12
#define Nn 80
#define CTERM 73.51508265637381f   // 0.5 * 80 * log(2*pi)
#define STA 84                     // fp32 LDS stride (336 B, 16B-aligned)

typedef __attribute__((ext_vector_type(8))) short short8;
typedef __attribute__((ext_vector_type(4))) float f32x4;

static __device__ __forceinline__ unsigned short f2bf(float f) {
    unsigned u = __builtin_bit_cast(unsigned, f);
    unsigned r = u + 0x7FFFu + ((u >> 16) & 1u);   // round-to-nearest-even
    return (unsigned short)(r >> 16);
}

// ============ Kernel 1 (R16): 6-wave (384-thr) interleaved prep — occupancy probe ======
// Identical 21-phase interleaved A+B structure as R15, modulus 8 -> 6.
// Rationale: occupancy counters show only 2 blocks/CU resident for >=256-thread blocks
// (R5/R6..R15 all ~50%); 768 blocks then run in 1.5 rounds. If 4x384-thread blocks fit,
// the half-round disappears. Masters: A-solve p -> wave p%6, B-solve p-1 -> wave (p-1)%6
// (adjacent integers never collide mod 6; wave-synchronous hand-offs preserved since the
// owner of column-group p IS the master of panel p under g = w mod 6).
__global__ __launch_bounds__(384, 6) void prep_kernel(
    const float* __restrict__ sigma, const float* __restrict__ mu,
    const float* __restrict__ x,
    uint4* __restrict__ wsWh,                              // [768][800] uint4
    float* __restrict__ wsV, float* __restrict__ wsL,
    uint4* __restrict__ Xh, int doX)
{
    __shared__ float Ls[Nn * STA];   // lower = L (Phase A), upper = W^T (Phase B)
    __shared__ float invd[Nn];
    __shared__ float mus[Nn];
    __shared__ float ldp[6];
    __shared__ float vps[6 * Nn];    // Phase C partial v

    const int bk  = blockIdx.x;
    const int tid = threadIdx.x;
    const int w   = tid >> 6;        // 0..5
    const int l   = tid & 63;
    const int r2  = l + 64;

    // ---- stage sigma: lower + diag-block only (c4 <= r+3) ----
    const float4* sp4 = (const float4*)(sigma + (size_t)bk * Nn * Nn);
    #pragma unroll
    for (int it = 0; it < 5; ++it) {
        int ci = tid + 384 * it;
        if (ci < 1600) {
            int r = ci / 20, c4 = 4 * (ci - 20 * r);
            if (c4 <= r + 3) {
                float4 v = sp4[ci];
                *(float4*)&Ls[r * STA + c4] = v;
            }
        }
    }
    if (tid < Nn) mus[tid] = mu[(size_t)bk * Nn + tid];
    __syncthreads();
    if (tid < Nn) Ls[tid * STA + tid] += 1e-5f;
    __syncthreads();

    // ---- Interleaved A (Cholesky) + B (inversion): 21 phases, 1 barrier each ----
    float ldacc = 0.0f;
    for (int p = 0; p <= 20; ++p) {
        const int j0 = 4 * p;            // A panel (valid p<20)
        const int i0 = 4 * (p - 1);      // B panel (valid p>=1)
        const int mA = p % 6;            // A master wave
        const int mB = (p + 5) % 6;      // = (p-1) mod 6, B master wave

        // ---- A-solve panel p (master wave p%6) ----
        if (p < 20 && w == mA) {
            float B00 = Ls[j0*STA+j0];
            float B10 = Ls[(j0+1)*STA+j0], B11 = Ls[(j0+1)*STA+j0+1];
            float B20 = Ls[(j0+2)*STA+j0], B21 = Ls[(j0+2)*STA+j0+1], B22 = Ls[(j0+2)*STA+j0+2];
            float B30 = Ls[(j0+3)*STA+j0], B31 = Ls[(j0+3)*STA+j0+1], B32 = Ls[(j0+3)*STA+j0+2], B33 = Ls[(j0+3)*STA+j0+3];
            float rv0 = rsqrtf(B00);
            float l10 = B10*rv0, l20 = B20*rv0, l30 = B30*rv0;
            float t11 = fmaf(-l10,l10,B11);                    float rv1 = rsqrtf(t11);
            float l21 = fmaf(-l20,l10,B21)*rv1;
            float l31 = fmaf(-l30,l10,B31)*rv1;
            float t22 = fmaf(-l21,l21,fmaf(-l20,l20,B22));     float rv2 = rsqrtf(t22);
            float l32 = fmaf(-l31,l21,fmaf(-l30,l20,B32))*rv2;
            float t33 = fmaf(-l32,l32,fmaf(-l31,l31,fmaf(-l30,l30,B33)));
            float rv3 = rsqrtf(t33);
            ldacc += 0.5f * (logf(B00) + logf(t11) + logf(t22) + logf(t33));
            if (l == 0) { invd[j0]=rv0; invd[j0+1]=rv1; invd[j0+2]=rv2; invd[j0+3]=rv3; }

            if (l >= j0) {
                float4 a = *(float4*)&Ls[l * STA + j0];
                float b0 = a.x * rv0;
                float b1 = fmaf(-l10, b0, a.y) * rv1;
                float b2 = fmaf(-l21, b1, fmaf(-l20, b0, a.z)) * rv2;
                float b3 = fmaf(-l32, b2, fmaf(-l31, b1, fmaf(-l30, b0, a.w))) * rv3;
                *(float4*)&Ls[l * STA + j0] = make_float4(b0, b1, b2, b3);
            }
            if (l < 16 && r2 >= j0) {
                float4 a = *(float4*)&Ls[r2 * STA + j0];
                float c0 = a.x * rv0;
                float c1 = fmaf(-l10, c0, a.y) * rv1;
                float c2 = fmaf(-l21, c1, fmaf(-l20, c0, a.z)) * rv2;
                float c3 = fmaf(-l32, c2, fmaf(-l31, c1, fmaf(-l30, c0, a.w))) * rv3;
                *(float4*)&Ls[r2 * STA + j0] = make_float4(c0, c1, c2, c3);
            }
        }

        // ---- B-solve panel p-1 (master wave (p-1)%6); first-touch identity ----
        if (p >= 1 && w == mB) {
            float m10 = Ls[(i0+1)*STA + i0];
            float m20 = Ls[(i0+2)*STA + i0];
            float m30 = Ls[(i0+3)*STA + i0];
            float m21 = Ls[(i0+2)*STA + i0+1];
            float m31 = Ls[(i0+3)*STA + i0+1];
            float m32 = Ls[(i0+3)*STA + i0+2];
            float4 iv = *(const float4*)&invd[i0];
            if (i0 + 3 >= l) {
                float4 a;
                if (l >= i0)
                    a = make_float4(l==i0?1.f:0.f, l==i0+1?1.f:0.f, l==i0+2?1.f:0.f, l==i0+3?1.f:0.f);
                else
                    a = *(float4*)&Ls[l * STA + i0];
                float w0 = a.x * iv.x;
                float w1 = fmaf(-w0, m10, a.y) * iv.y;
                float w2 = fmaf(-w1, m21, fmaf(-w0, m20, a.z)) * iv.z;
                float w3 = fmaf(-w2, m32, fmaf(-w1, m31, fmaf(-w0, m30, a.w))) * iv.w;
                *(float4*)&Ls[l * STA + i0] = make_float4(w0, w1, w2, w3);
            }
            if (l < 16 && i0 + 3 >= r2) {
                float4 a;
                if (r2 >= i0)
                    a = make_float4(r2==i0?1.f:0.f, r2==i0+1?1.f:0.f, r2==i0+2?1.f:0.f, r2==i0+3?1.f:0.f);
                else
                    a = *(float4*)&Ls[r2 * STA + i0];
                float v0 = a.x * iv.x;
                float v1 = fmaf(-v0, m10, a.y) * iv.y;
                float v2 = fmaf(-v1, m21, fmaf(-v0, m20, a.z)) * iv.z;
                float v3 = fmaf(-v2, m32, fmaf(-v1, m31, fmaf(-v0, m30, a.w))) * iv.w;
                *(float4*)&Ls[r2 * STA + i0] = make_float4(v0, v1, v2, v3);
            }
        }
        __syncthreads();   // the ONLY barrier this phase

        // ---- A-update panel p: lower-only, lane l -> row 4g+l (owned g = w mod 6) ----
        if (p < 20) {
            const int gs0 = p + 1;
            int d = (w - gs0) % 6; if (d < 0) d += 6;
            const int g0 = gs0 + d;
            for (int g = g0; g < 20; g += 6) {
                const int cb = 4 * g;
                float4 q0 = *(const float4*)&Ls[(cb+0) * STA + j0];
                float4 q1 = *(const float4*)&Ls[(cb+1) * STA + j0];
                float4 q2 = *(const float4*)&Ls[(cb+2) * STA + j0];
                float4 q3 = *(const float4*)&Ls[(cb+3) * STA + j0];
                {
                    const int R = cb + l;
                    if (R < Nn) {
                        float4 pv = *(const float4*)&Ls[R * STA + j0];
                        float4 t  = *(float4*)&Ls[R * STA + cb];
                        t.x = fmaf(-pv.x,q0.x, fmaf(-pv.y,q0.y, fmaf(-pv.z,q0.z, fmaf(-pv.w,q0.w, t.x))));
                        t.y = fmaf(-pv.x,q1.x, fmaf(-pv.y,q1.y, fmaf(-pv.z,q1.z, fmaf(-pv.w,q1.w, t.y))));
                        t.z = fmaf(-pv.x,q2.x, fmaf(-pv.y,q2.y, fmaf(-pv.z,q2.z, fmaf(-pv.w,q2.w, t.z))));
                        t.w = fmaf(-pv.x,q3.x, fmaf(-pv.y,q3.y, fmaf(-pv.z,q3.z, fmaf(-pv.w,q3.w, t.w))));
                        *(float4*)&Ls[R * STA + cb] = t;
                    }
                }
                if (cb + 64 < Nn) {
                    const int R = cb + 64 + l;
                    if (R < Nn) {
                        float4 pv = *(const float4*)&Ls[R * STA + j0];
                        float4 t  = *(float4*)&Ls[R * STA + cb];
                        t.x = fmaf(-pv.x,q0.x, fmaf(-pv.y,q0.y, fmaf(-pv.z,q0.z, fmaf(-pv.w,q0.w, t.x))));
                        t.y = fmaf(-pv.x,q1.x, fmaf(-pv.y,q1.y, fmaf(-pv.z,q1.z, fmaf(-pv.w,q1.w, t.y))));
                        t.z = fmaf(-pv.x,q2.x, fmaf(-pv.y,q2.y, fmaf(-pv.z,q2.z, fmaf(-pv.w,q2.w, t.z))));
                        t.w = fmaf(-pv.x,q3.x, fmaf(-pv.y,q3.y, fmaf(-pv.z,q3.z, fmaf(-pv.w,q3.w, t.w))));
                        *(float4*)&Ls[R * STA + cb] = t;
                    }
                }
            }
        }

        // ---- B-update panel p-1: upper, first-touch zero (owned g = w mod 6, g >= p) --
        if (p >= 1) {
            const bool b1a = (i0 + 3 >= l);
            const bool b2a = (l < 16) && (i0 + 3 >= r2);
            if (b1a | b2a) {
                float4 wv = make_float4(0.f,0.f,0.f,0.f), vv = make_float4(0.f,0.f,0.f,0.f);
                if (b1a) wv = *(float4*)&Ls[l * STA + i0];
                if (b2a) vv = *(float4*)&Ls[r2 * STA + i0];
                const int gs0 = p;
                int d = (w - gs0) % 6; if (d < 0) d += 6;
                const int g0 = gs0 + d;
                for (int g = g0; g < 20; g += 6) {
                    const int cb = 4 * g;
                    float4 q0 = *(const float4*)&Ls[(cb+0) * STA + i0];
                    float4 q1 = *(const float4*)&Ls[(cb+1) * STA + i0];
                    float4 q2 = *(const float4*)&Ls[(cb+2) * STA + i0];
                    float4 q3 = *(const float4*)&Ls[(cb+3) * STA + i0];
                    if (b1a) {
                        float4 t;
                        if (l >= i0) t = make_float4(0.f, 0.f, 0.f, 0.f);   // first touch
                        else         t = *(float4*)&Ls[l * STA + cb];
                        t.x = fmaf(-wv.x,q0.x, fmaf(-wv.y,q0.y, fmaf(-wv.z,q0.z, fmaf(-wv.w,q0.w, t.x))));
                        t.y = fmaf(-wv.x,q1.x, fmaf(-wv.y,q1.y, fmaf(-wv.z,q1.z, fmaf(-wv.w,q1.w, t.y))));
                        t.z = fmaf(-wv.x,q2.x, fmaf(-wv.y,q2.y, fmaf(-wv.z,q2.z, fmaf(-wv.w,q2.w, t.z))));
                        t.w = fmaf(-wv.x,q3.x, fmaf(-wv.y,q3.y, fmaf(-wv.z,q3.z, fmaf(-wv.w,q3.w, t.w))));
                        *(float4*)&Ls[l * STA + cb] = t;
                    }
                    if (b2a) {
                        float4 t;
                        if (r2 >= i0) t = make_float4(0.f, 0.f, 0.f, 0.f);
                        else          t = *(float4*)&Ls[r2 * STA + cb];
                        t.x = fmaf(-vv.x,q0.x, fmaf(-vv.y,q0.y, fmaf(-vv.z,q0.z, fmaf(-vv.w,q0.w, t.x))));
                        t.y = fmaf(-vv.x,q1.x, fmaf(-vv.y,q1.y, fmaf(-vv.z,q1.z, fmaf(-vv.w,q1.w, t.y))));
                        t.z = fmaf(-vv.x,q2.x, fmaf(-vv.y,q2.y, fmaf(-vv.z,q2.z, fmaf(-vv.w,q2.w, t.z))));
                        t.w = fmaf(-vv.x,q3.x, fmaf(-vv.y,q3.y, fmaf(-vv.z,q3.z, fmaf(-vv.w,q3.w, t.w))));
                        *(float4*)&Ls[r2 * STA + cb] = t;
                    }
                }
            }
        }
    }
    if (l == 0) ldp[w] = ldacc;
    __syncthreads();
    if (tid == 0) wsL[bk] = ldp[0]+ldp[1]+ldp[2]+ldp[3]+ldp[4]+ldp[5];
    __syncthreads();

    // ---- Phase C: v = W*mu (mask c<=row; storage-lower holds L); 6-way strided ----
    {
        float s1 = 0.f, s2 = 0.f;
        for (int c = w; c < Nn; c += 6) {
            float mc = mus[c];
            float e1 = (c <= l)  ? Ls[c * STA + l]  : 0.f;   // W[l][c]
            s1 = fmaf(e1, mc, s1);
            if (l < 16) {
                float e2 = (c <= r2) ? Ls[c * STA + r2] : 0.f;
                s2 = fmaf(e2, mc, s2);
            }
        }
        vps[w * Nn + l] = s1;
        if (l < 16) vps[w * Nn + r2] = s2;
        __syncthreads();
        if (tid < Nn) {
            float acc = 0.f;
            #pragma unroll
            for (int ww = 0; ww < 6; ++ww) acc += vps[ww * Nn + tid];
            wsV[(size_t)bk * Nn + tid] = acc;
        }
    }

    // ---- Fragment pack (mask m>=kb+j; split 6 ways) — hi only ----
    const int n = l & 15, quad = l >> 4;
    uint4* ph = wsWh + (size_t)bk * 800;
    for (int f = w; f < 10; f += 6) {
        int ks = f / 5, mt = f - 5 * ks;
        int m = 16 * mt + n, kb = 32 * ks + 8 * quad;
        unsigned hh[8];
        #pragma unroll
        for (int j = 0; j < 8; ++j) {
            float wj = (m >= kb + j) ? Ls[(kb + j) * STA + m] : 0.f;   // = W[m][kb+j]
            hh[j] = f2bf(wj);
        }
        ph[f*64 + l] = make_uint4(hh[0]|(hh[1]<<16), hh[2]|(hh[3]<<16), hh[4]|(hh[5]<<16), hh[6]|(hh[7]<<16));
    }
    if (w < 5) {
        int mt = w;
        if (quad < 2) {
            int m = 16 * mt + n, kb = 64 + 8 * quad;
            unsigned hh[8];
            #pragma unroll
            for (int j = 0; j < 8; ++j) {
                float wj = (m >= kb + j) ? Ls[(kb + j) * STA + m] : 0.f;
                hh[j] = f2bf(wj);
            }
            ph[640 + mt*32 + l] = make_uint4(hh[0]|(hh[1]<<16), hh[2]|(hh[3]<<16), hh[4]|(hh[5]<<16), hh[6]|(hh[7]<<16));
        }
    }

    // ---- Fused tail: x -> bf16 HI-ONLY B-fragments; coalesced 1KB/wave bursts ----
    if (doX) {
        const int wid = bk * 6 + w;            // 0..4607 wave-slots
        const int qd = l >> 4, n2 = l & 15;
        #pragma unroll
        for (int it = 0; it < 3; ++it) {
            int G = wid + 4608 * it;            // (b2, sg, ks) groups: 64*63*3 = 12096
            if (G >= 12096) break;
            int b2  = G / 189;
            int rem = G - b2 * 189;
            int sg  = rem / 3, ks = rem - 3 * sg;
            int s   = sg * 16 + n2;
            int k0  = 32 * ks + 8 * qd;
            float d[8] = {0.f,0.f,0.f,0.f,0.f,0.f,0.f,0.f};
            if (s < Ss) {
                const float* xp = x + ((size_t)b2 * Ss + s) * Nn + k0;
                float4 f0 = *(const float4*)xp;
                float4 f1 = *(const float4*)(xp + 4);
                d[0]=f0.x; d[1]=f0.y; d[2]=f0.z; d[3]=f0.w;
                d[4]=f1.x; d[5]=f1.y; d[6]=f1.z; d[7]=f1.w;
            }
            unsigned hh[8];
            #pragma unroll
            for (int j = 0; j < 8; ++j) hh[j] = f2bf(d[j]);
            size_t slot = ((size_t)(b2 * 64 + sg) * 3 + ks) * 64 + l;
            Xh[slot] = make_uint4(hh[0]|(hh[1]<<16), hh[2]|(hh[3]<<16), hh[4]|(hh[5]<<16), hh[6]|(hh[7]<<16));
        }
    }
}

// ============ Kernel 2 (full tier, R14-validated): 8-wave ll2, 1-term MFMA =============
__global__ __launch_bounds__(512) void ll_kernel2(
    const uint4* __restrict__ Xh,
    const uint4* __restrict__ wsWh,
    const float* __restrict__ wsV, const float* __restrict__ wsL,
    float* __restrict__ out)
{
    __shared__ uint4 WhL[960];   // [0..640): ks=0,1; [640..960): ks=2 expanded
    const int b = blockIdx.x;
    const int k = blockIdx.y;
    const int bk = b * Kk + k;
    const int tid = threadIdx.x;
    const int wv = tid >> 6, lane = tid & 63;
    const int n = lane & 15, quad = lane >> 4;

    const uint4* gh = wsWh + (size_t)bk * 800;
    #pragma unroll
    for (int it = 0; it < 2; ++it) {
        int i = tid + 512 * it;
        if (i < 640) WhL[i] = gh[i];
    }
    if (tid < 320) {
        int mt = tid >> 6, ln = tid & 63, qd = (ln >> 4);
        uint4 vh = make_uint4(0,0,0,0);
        if (qd < 2) vh = gh[640 + mt*32 + ln];
        WhL[640 + tid] = vh;
    }
    __syncthreads();

    const float ld = wsL[bk];
    f32x4 vf[5];
    #pragma unroll
    for (int mt = 0; mt < 5; ++mt)
        vf[mt] = *(const f32x4*)&wsV[(size_t)bk * Nn + 16*mt + 4*quad];

    for (int it = 0; it < 4; ++it) {
        const int sg0 = wv * 8 + it * 2;
        short8 bh[2][3];
        #pragma unroll
        for (int t = 0; t < 2; ++t)
            #pragma unroll
            for (int ks = 0; ks < 3; ++ks) {
                size_t base = ((size_t)(b * 64 + sg0 + t) * 3 + ks) * 64 + lane;
                bh[t][ks] = __builtin_bit_cast(short8, Xh[base]);
            }

        f32x4 acc[2][5];
        #pragma unroll
        for (int t = 0; t < 2; ++t)
            #pragma unroll
            for (int mt = 0; mt < 5; ++mt) acc[t][mt] = (f32x4){0.f,0.f,0.f,0.f};

        #pragma unroll
        for (int ks = 0; ks < 3; ++ks) {
            #pragma unroll
            for (int mt = 0; mt < 5; ++mt) {
                const int fi = (ks < 2) ? (ks*5 + mt)*64 + lane : 640 + mt*64 + lane;
                short8 wh = __builtin_bit_cast(short8, WhL[fi]);
                #pragma unroll
                for (int t = 0; t < 2; ++t)
                    acc[t][mt] = __builtin_amdgcn_mfma_f32_16x16x32_bf16(wh, bh[t][ks], acc[t][mt], 0, 0, 0);
            }
        }

        #pragma unroll
        for (int t = 0; t < 2; ++t) {
            float q2 = 0.f;
            #pragma unroll
            for (int mt = 0; mt < 5; ++mt)
                #pragma unroll
                for (int r = 0; r < 4; ++r) {
                    float y = acc[t][mt][r] - vf[mt][r];
                    q2 = fmaf(y, y, q2);
                }
            q2 += __shfl_xor(q2, 16, 64);
            q2 += __shfl_xor(q2, 32, 64);
            int gs = (sg0 + t) * 16 + n;
            if (lane < 16 && gs < Ss)
                out[((size_t)b * Ss + gs) * Kk + k] = -0.5f * q2 - ld - CTERM;
        }
    }
}

// ============ Kernel 2 (mid tier): zero-LDS 1-term MFMA with in-kernel x conversion ====
__global__ __launch_bounds__(256) void ll_kernel(
    const float* __restrict__ x,
    const uint4* __restrict__ wsWh,
    const float* __restrict__ wsV, const float* __restrict__ wsL,
    float* __restrict__ out)
{
    const int b    = blockIdx.x;
    const int st   = blockIdx.y;
    const int tid  = threadIdx.x;
    const int wv   = tid >> 6, lane = tid & 63;
    const int n    = lane & 15, quad = lane >> 4;
    const int sbase = st * 128 + wv * 32;

    short8 xh[2][3];
    #pragma unroll
    for (int t = 0; t < 2; ++t) {
        int gs = sbase + 16 * t + n;
        #pragma unroll
        for (int ks = 0; ks < 3; ++ks) {
            int kb = 32 * ks + 8 * quad;
            float d[8] = {0.f,0.f,0.f,0.f,0.f,0.f,0.f,0.f};
            if (gs < Ss && kb < Nn) {
                const float* xp = x + ((size_t)b * Ss + gs) * Nn + kb;
                float4 f0 = *(const float4*)xp;
                float4 f1 = *(const float4*)(xp + 4);
                d[0]=f0.x; d[1]=f0.y; d[2]=f0.z; d[3]=f0.w;
                d[4]=f1.x; d[5]=f1.y; d[6]=f1.z; d[7]=f1.w;
            }
            short8 h;
            #pragma unroll
            for (int j = 0; j < 8; ++j) h[j] = (short)f2bf(d[j]);
            xh[t][ks] = h;
        }
    }

    for (int k = 0; k < Kk; ++k) {
        const int bk = b * Kk + k;
        const uint4* ah_p = wsWh + (size_t)bk * 800;

        f32x4 acc[2][5];
        #pragma unroll
        for (int t = 0; t < 2; ++t)
            #pragma unroll
            for (int mt = 0; mt < 5; ++mt) acc[t][mt] = (f32x4){0.f,0.f,0.f,0.f};

        #pragma unroll
        for (int ks = 0; ks < 3; ++ks) {
            short8 ah[5];
            if (ks < 2) {
                #pragma unroll
                for (int mt = 0; mt < 5; ++mt)
                    ah[mt] = __builtin_bit_cast(short8, ah_p[(ks*5 + mt)*64 + lane]);
            } else {
                #pragma unroll
                for (int mt = 0; mt < 5; ++mt) {
                    uint4 zh = make_uint4(0,0,0,0);
                    if (quad < 2) zh = ah_p[640 + mt*32 + lane];
                    ah[mt] = __builtin_bit_cast(short8, zh);
                }
            }
            #pragma unroll
            for (int mt = 0; mt < 5; ++mt)
                #pragma unroll
                for (int t = 0; t < 2; ++t)
                    acc[t][mt] = __builtin_amdgcn_mfma_f32_16x16x32_bf16(ah[mt], xh[t][ks], acc[t][mt], 0, 0, 0);
        }

        float ld = wsL[bk];
        f32x4 vf[5];
        #pragma unroll
        for (int mt = 0; mt < 5; ++mt)
            vf[mt] = *(const f32x4*)&wsV[(size_t)bk * Nn + 16*mt + 4*quad];
        #pragma unroll
        for (int t = 0; t < 2; ++t) {
            float q2 = 0.f;
            #pragma unroll
            for (int mt = 0; mt < 5; ++mt)
                #pragma unroll
                for (int r = 0; r < 4; ++r) {
                    float y = acc[t][mt][r] - vf[mt][r];
                    q2 = fmaf(y, y, q2);
                }
            q2 += __shfl_xor(q2, 16, 64);
            q2 += __shfl_xor(q2, 32, 64);
            int gs = sbase + 16 * t + n;
            if (lane < 16 && gs < Ss)
                out[((size_t)b * Ss + gs) * Kk + k] = -0.5f * q2 - ld - CTERM;
        }
    }
}

// ============ Fallback (ws too small) ==================================================
#define ST1 81
__global__ __launch_bounds__(256) void mvn_ll_fallback(
    const float* __restrict__ x, const float* __restrict__ mu,
    const float* __restrict__ sigma, float* __restrict__ out)
{
    __shared__ float Ls[Nn * ST1];
    __shared__ float invd[Nn];
    __shared__ float mus[Nn];
    __shared__ float logdet_s;

    const int bk = blockIdx.x, b = bk / Kk, k = bk - b * Kk;
    const int tid = threadIdx.x, nt = blockDim.x;

    const float* sp = sigma + (size_t)bk * Nn * Nn;
    for (int t = tid; t < Nn * Nn; t += nt) Ls[(t / Nn) * ST1 + (t % Nn)] = sp[t];
    if (tid < Nn) mus[tid] = mu[(size_t)bk * Nn + tid];
    __syncthreads();
    if (tid < Nn) Ls[tid * ST1 + tid] += 1e-5f;
    __syncthreads();
    for (int j = 0; j < Nn; ++j) {
        if (tid == 0) {
            float d = sqrtf(Ls[j * ST1 + j]);
            Ls[j * ST1 + j] = d; invd[j] = 1.0f / d;
        }
        __syncthreads();
        const float inv = invd[j];
        for (int i = j + 1 + tid; i < Nn; i += nt) Ls[i * ST1 + j] *= inv;
        __syncthreads();
        for (int t = tid; t < Nn * Nn; t += nt) {
            int r = t / Nn, c = t % Nn;
            if (r > j && c > j && c <= r)
                Ls[r * ST1 + c] -= Ls[r * ST1 + j] * Ls[c * ST1 + j];
        }
        __syncthreads();
    }
    if (tid == 0) {
        float a = 0.f; for (int j = 0; j < Nn; ++j) a += logf(Ls[j * ST1 + j]);
        logdet_s = a;
    }
    __syncthreads();
    const float ld = logdet_s;
    for (int s = tid; s < Ss; s += nt) {
        const float4* xp = (const float4*)(x + ((size_t)b * Ss + s) * Nn);
        float a[Nn];
        #pragma unroll
        for (int q = 0; q < Nn / 4; ++q) {
            float4 v = xp[q];
            a[4*q+0] = v.x - mus[4*q+0]; a[4*q+1] = v.y - mus[4*q+1];
            a[4*q+2] = v.z - mus[4*q+2]; a[4*q+3] = v.w - mus[4*q+3];
        }
        #pragma unroll
        for (int i = 0; i < Nn; ++i) {
            float t = a[i];
            #pragma unroll
            for (int j = 0; j < i; ++j) t = fmaf(-Ls[i * ST1 + j], a[j], t);
            a[i] = t * invd[i];
        }
        float quad = 0.f;
        #pragma unroll
        for (int i = 0; i < Nn; ++i) quad = fmaf(a[i], a[i], quad);
        out[((size_t)b * Ss + s) * Kk + k] = -0.5f * quad - ld - CTERM;
    }
}

extern "C" void kernel_launch(void* const* d_in, const int* in_sizes, int n_in,
                              void* d_out, int out_size, void* d_ws, size_t ws_size,
                              hipStream_t stream) {
    const float* x     = (const float*)d_in[0];
    const float* mu    = (const float*)d_in[1];
    const float* sigma = (const float*)d_in[2];
    float* out = (float*)d_out;

    const size_t nBK   = (size_t)Bb * Kk;            // 768
    const size_t nWu4  = nBK * 800;                  // W frag uint4s (hi only)
    const size_t nXu4  = (size_t)Bb * 64 * 3 * 64;   // 786432 x-frag uint4s (hi only)
    const size_t need_mid  = nWu4 * 16 + nBK * Nn * 4 + nBK * 4;
    const size_t need_full = need_mid + nXu4 * 16;

    if (ws_size >= need_full) {
        uint4* wsWh = (uint4*)d_ws;
        uint4* Xh   = wsWh + nWu4;
        float* wsV  = (float*)(Xh + nXu4);
        float* wsL  = wsV + nBK * Nn;
        prep_kernel<<<dim3(Bb * Kk), dim3(384), 0, stream>>>(
            sigma, mu, x, wsWh, wsV, wsL, Xh, 1);
        ll_kernel2<<<dim3(Bb, Kk), dim3(512), 0, stream>>>(Xh, wsWh, wsV, wsL, out);
    } else if (ws_size >= need_mid) {
        uint4* wsWh = (uint4*)d_ws;
        float* wsV  = (float*)(wsWh + nWu4);
        float* wsL  = wsV + nBK * Nn;
        prep_kernel<<<dim3(Bb * Kk), dim3(384), 0, stream>>>(
            sigma, mu, x, wsWh, wsV, wsL, (uint4*)nullptr, 0);
        ll_kernel<<<dim3(Bb, 8), dim3(256), 0, stream>>>(x, wsWh, wsV, wsL, out);
    } else {
        mvn_ll_fallback<<<dim3(Bb * Kk), dim3(256), 0, stream>>>(x, mu, sigma, out);
    }
}